// Round 16
// baseline (57.203 us; speedup 1.0000x reference)
//
#include <hip/hip_runtime.h>

// RBF Gram via single-pass fp16 MFMA with quantization-cancelling norms.
//   P1: x (fp32 [N][64]) -> H (fp16, XOR-swizzled per 128-row chunk), sq = ||fp16(x)||^2.
//   P2: 128x256 tile per block (A + B0 + B1 staged, 48 KB), 4 waves; wave owns
//       32 rows x 256 cols via two sequential K-passes (acc[2][2][8], 128 VGPR).
//       Epilogue: exp -> wave-private 16 KB LDS bounce -> readback so EACH wave
//       store = 64 lanes x 16 B = 1 KB CONTIGUOUS (the fillBuffer pattern that
//       measures 7.0 TB/s on this chip). One barrier post-K (operand LDS reused).

#define GAMMA 0.5f

typedef __attribute__((ext_vector_type(8))) _Float16 half8;
typedef __attribute__((ext_vector_type(4))) float f32x4;

// ---------------- Phase 1: fp16 quantize + swizzle + quantized norms ----------------
__global__ __launch_bounds__(256) void quant_kernel(const float* __restrict__ x,
                                                    unsigned short* __restrict__ H,
                                                    float* __restrict__ sq) {
    int tid = blockIdx.x * 256 + threadIdx.x;   // one float4 (4 elems of one row)
    int row = tid >> 4, c4 = tid & 15;
    float4 v = ((const float4*)x)[tid];
    float e[4] = {v.x, v.y, v.z, v.w};
    unsigned short hb[4];
    float s = 0.f;
    #pragma unroll
    for (int i = 0; i < 4; ++i) {
        _Float16 h = (_Float16)e[i];            // RNE
        float hf = (float)h;
        s = fmaf(hf, hf, s);                    // norm of the QUANTIZED vector
        hb[i] = __builtin_bit_cast(unsigned short, h);
    }
    int rr = row & 127;
    size_t base = (size_t)(row >> 7) * 16384;
    int b = (rr * 128 + c4 * 8) ^ ((rr & 7) << 4);
    uint2 hw = {(unsigned)hb[0] | ((unsigned)hb[1] << 16),
                (unsigned)hb[2] | ((unsigned)hb[3] << 16)};
    *(uint2*)((char*)H + base + b) = hw;
    s += __shfl_xor(s, 1); s += __shfl_xor(s, 2);
    s += __shfl_xor(s, 4); s += __shfl_xor(s, 8);
    if (c4 == 0) sq[row] = s;
}

// ---------------- Phase 2: 128x256 tile, 1KB-run stores via LDS bounce ----------------
__global__ __launch_bounds__(256, 2) void rbf_mfma11(const unsigned short* __restrict__ H,
                                                     const float* __restrict__ sq,
                                                     float* __restrict__ out, int N) {
    __shared__ __align__(16) char smem[65536];
    unsigned short* Ah  = (unsigned short*)smem;              // 16 KB (rows i0..i0+127)
    unsigned short* Bh0 = (unsigned short*)(smem + 16384);    // 16 KB (rows j0..j0+127)
    unsigned short* Bh1 = (unsigned short*)(smem + 32768);    // 16 KB (rows j0+128..j0+255)
    // after the post-K barrier, smem = 4 x 16KB wave-private bounce buffers

    const int tid = threadIdx.x;
    const int i0 = blockIdx.y * 128, j0 = blockIdx.x * 256;
    const int w = tid >> 6, lane = tid & 63;
    const int fr = lane & 15, kg = lane >> 4;
    const int wr = w * 32;                      // wave owns rows wr..wr+31, all 256 cols

    // ---- stage: linear 48KB copy (swizzle pre-baked; 256 B-rows are contiguous) ----
    {
        const uint4* ga = (const uint4*)(H + (size_t)i0 * 64);
        const uint4* gb = (const uint4*)(H + (size_t)j0 * 64);
        #pragma unroll
        for (int t = 0; t < 4; ++t)
            ((uint4*)Ah)[t * 256 + tid] = ga[t * 256 + tid];
        #pragma unroll
        for (int t = 0; t < 8; ++t)
            ((uint4*)Bh0)[t * 256 + tid] = gb[t * 256 + tid];   // fills Bh0 then Bh1
    }
    __syncthreads();

    // ---- K-loops: 2 tiles x 2 ksteps, swapped operands -> D^T ----
    f32x4 acc[2][2][8];   // [tile][p(row-frag)][q(col-frag)]
    #pragma unroll
    for (int t = 0; t < 2; ++t)
        #pragma unroll
        for (int p = 0; p < 2; ++p)
            #pragma unroll
            for (int q = 0; q < 8; ++q) acc[t][p][q] = (f32x4)(0.f);

    #pragma unroll
    for (int t = 0; t < 2; ++t) {
        const unsigned short* Bt = t ? Bh1 : Bh0;
        #pragma unroll
        for (int ks = 0; ks < 2; ++ks) {
            const int kb = ks * 64 + kg * 16;
            half8 ah[2], bh[8];
            #pragma unroll
            for (int p = 0; p < 2; ++p) {
                int R = wr + p * 16 + fr;
                int off = (R * 128 + kb) ^ ((R & 7) << 4);
                ah[p] = *(const half8*)((const char*)Ah + off);
            }
            #pragma unroll
            for (int q = 0; q < 8; ++q) {
                int R = q * 16 + fr;
                int off = (R * 128 + kb) ^ ((R & 7) << 4);
                bh[q] = *(const half8*)((const char*)Bt + off);
            }
            #pragma unroll
            for (int p = 0; p < 2; ++p)
                #pragma unroll
                for (int q = 0; q < 8; ++q)
                    acc[t][p][q] = __builtin_amdgcn_mfma_f32_16x16x32_f16(bh[q], ah[p], acc[t][p][q], 0, 0, 0);
        }
    }

    __syncthreads();   // all waves done reading operands; smem becomes bounce space
    float* wbuf = (float*)smem + w * 4096;      // wave-private 16 KB (16 rows x 256 cols)

    #pragma unroll
    for (int p = 0; p < 2; ++p) {
        // exp + swizzled ds_write: lane (fr,kg) holds row p*16+fr, cols t*128+q*16+kg*4..+3
        float sa = sq[i0 + wr + p * 16 + fr];
        #pragma unroll
        for (int t = 0; t < 2; ++t) {
            #pragma unroll
            for (int q = 0; q < 8; ++q) {
                int c = t * 128 + q * 16 + kg * 4;
                float4 sb = *(const float4*)&sq[j0 + c];
                f32x4 a = acc[t][p][q];
                float4 r;
                r.x = __expf(-GAMMA * fmaxf(fmaf(-2.f, a[0], sa + sb.x), 0.f));
                r.y = __expf(-GAMMA * fmaxf(fmaf(-2.f, a[1], sa + sb.y), 0.f));
                r.z = __expf(-GAMMA * fmaxf(fmaf(-2.f, a[2], sa + sb.z), 0.f));
                r.w = __expf(-GAMMA * fmaxf(fmaf(-2.f, a[3], sa + sb.w), 0.f));
                *(float4*)&wbuf[fr * 256 + (c ^ ((fr & 7) << 2))] = r;
            }
        }
        // readback + store: one FULL 256-col row = 1 KB contiguous per wave-instr
        // (same-wave RAW/WAR through wbuf ordered by in-order DS pipe + lgkmcnt)
        #pragma unroll
        for (int rl = 0; rl < 16; ++rl) {
            float4 v = *(const float4*)&wbuf[rl * 256 + ((lane * 4) ^ ((rl & 7) << 2))];
            int grow = i0 + wr + p * 16 + rl;
            *(float4*)(out + (size_t)grow * N + j0 + lane * 4) = v;
        }
    }
}

extern "C" void kernel_launch(void* const* d_in, const int* in_sizes, int n_in,
                              void* d_out, int out_size, void* d_ws, size_t ws_size,
                              hipStream_t stream) {
    (void)n_in; (void)ws_size; (void)out_size;
    const float* x = (const float*)d_in[0];
    float* out = (float*)d_out;
    const int K = 64;
    const int N = in_sizes[0] / K;   // 8192

    unsigned short* H = (unsigned short*)d_ws;       // N*64 fp16 = 1 MB
    float* sq = (float*)(H + (size_t)N * K);         // 32 KB

    quant_kernel<<<dim3(N * K / 4 / 256), dim3(256), 0, stream>>>(x, H, sq);
    // grid: 32 x 64 = 2048 blocks, 64 KB LDS -> 2 blocks/CU
    rbf_mfma11<<<dim3(N / 256, N / 128), dim3(256), 0, stream>>>(H, sq, out, N);
}

// Round 18
// 55.912 us; speedup vs baseline: 1.0231x; 1.0231x over previous
//
#include <hip/hip_runtime.h>

// RBF Gram via single-pass fp16 MFMA with quantization-cancelling norms.
//   P1: x (fp32 [N][64]) -> H (fp16, XOR-swizzled per 128-row chunk), sq = ||fp16(x)||^2.
//   P2: 128x128 tile, 4 waves; wave w owns rows w*32..w*32+31 x all 128 cols.
//       After MFMA: exp -> wave-private 8KB LDS bounce (reuse Ah/Bh, one barrier)
//       -> readback -> 512B-run stores, NONTEMPORAL (nt bypasses L2 allocate;
//       single-variable A/B vs R15's 54.1 us to test the L2-write-path theory).

#define GAMMA 0.5f

typedef __attribute__((ext_vector_type(8))) _Float16 half8;
typedef __attribute__((ext_vector_type(4))) float f32x4;

// ---------------- Phase 1: fp16 quantize + swizzle + quantized norms ----------------
__global__ __launch_bounds__(256) void quant_kernel(const float* __restrict__ x,
                                                    unsigned short* __restrict__ H,
                                                    float* __restrict__ sq) {
    int tid = blockIdx.x * 256 + threadIdx.x;   // one float4 (4 elems of one row)
    int row = tid >> 4, c4 = tid & 15;
    float4 v = ((const float4*)x)[tid];
    float e[4] = {v.x, v.y, v.z, v.w};
    unsigned short hb[4];
    float s = 0.f;
    #pragma unroll
    for (int i = 0; i < 4; ++i) {
        _Float16 h = (_Float16)e[i];            // RNE
        float hf = (float)h;
        s = fmaf(hf, hf, s);                    // norm of the QUANTIZED vector
        hb[i] = __builtin_bit_cast(unsigned short, h);
    }
    int rr = row & 127;
    size_t base = (size_t)(row >> 7) * 16384;
    int b = (rr * 128 + c4 * 8) ^ ((rr & 7) << 4);
    uint2 hw = {(unsigned)hb[0] | ((unsigned)hb[1] << 16),
                (unsigned)hb[2] | ((unsigned)hb[3] << 16)};
    *(uint2*)((char*)H + base + b) = hw;
    s += __shfl_xor(s, 1); s += __shfl_xor(s, 2);
    s += __shfl_xor(s, 4); s += __shfl_xor(s, 8);
    if (c4 == 0) sq[row] = s;
}

// ---------------- Phase 2: 128x128 tile, row-run NT stores via LDS bounce ----------------
__global__ __launch_bounds__(256, 4) void rbf_mfma12(const unsigned short* __restrict__ H,
                                                     const float* __restrict__ sq,
                                                     float* __restrict__ out, int N) {
    __shared__ __align__(16) char smem[32768];
    unsigned short* Ah = (unsigned short*)smem;             // 16 KB
    unsigned short* Bh = (unsigned short*)(smem + 16384);   // 16 KB
    // after the post-K barrier, smem is reused as 4 x 8KB wave-private bounce buffers

    const int tid = threadIdx.x;
    const int i0 = blockIdx.y * 128, j0 = blockIdx.x * 128;
    const int w = tid >> 6, lane = tid & 63;
    const int fr = lane & 15, kg = lane >> 4;
    const int wr = w * 32;                      // wave owns rows wr..wr+31, all 128 cols

    // ---- stage: linear 32KB copy (swizzle pre-baked in global layout) ----
    {
        const uint4* ga = (const uint4*)(H + (size_t)i0 * 64);
        const uint4* gb = (const uint4*)(H + (size_t)j0 * 64);
        #pragma unroll
        for (int t = 0; t < 4; ++t) {
            ((uint4*)Ah)[t * 256 + tid] = ga[t * 256 + tid];
            ((uint4*)Bh)[t * 256 + tid] = gb[t * 256 + tid];
        }
    }
    __syncthreads();

    // ---- K-loop: 2 ksteps, swapped operands -> D^T; acc[p][q] = rows x col-frags ----
    f32x4 acc[2][8];
    #pragma unroll
    for (int p = 0; p < 2; ++p)
        #pragma unroll
        for (int q = 0; q < 8; ++q) acc[p][q] = (f32x4)(0.f);

    #pragma unroll
    for (int ks = 0; ks < 2; ++ks) {
        const int kb = ks * 64 + kg * 16;
        half8 ah[2], bh[8];
        #pragma unroll
        for (int p = 0; p < 2; ++p) {
            int R = wr + p * 16 + fr;
            int off = (R * 128 + kb) ^ ((R & 7) << 4);
            ah[p] = *(const half8*)((const char*)Ah + off);
        }
        #pragma unroll
        for (int q = 0; q < 8; ++q) {
            int R = q * 16 + fr;
            int off = (R * 128 + kb) ^ ((R & 7) << 4);
            bh[q] = *(const half8*)((const char*)Bh + off);
        }
        #pragma unroll
        for (int p = 0; p < 2; ++p)
            #pragma unroll
            for (int q = 0; q < 8; ++q)
                acc[p][q] = __builtin_amdgcn_mfma_f32_16x16x32_f16(bh[q], ah[p], acc[p][q], 0, 0, 0);
    }

    __syncthreads();   // all waves done reading Ah/Bh; smem becomes bounce space
    float* wbuf = (float*)smem + w * 2048;      // wave-private 8 KB (16 rows x 128 cols)

    #pragma unroll
    for (int p = 0; p < 2; ++p) {
        // exp + swizzled ds_write: lane (fr,kg) holds rows p*16+fr, cols q*16+kg*4..+3
        float sa = sq[i0 + wr + p * 16 + fr];
        #pragma unroll
        for (int q = 0; q < 8; ++q) {
            int c = q * 16 + kg * 4;
            float4 sb = *(const float4*)&sq[j0 + c];
            f32x4 a = acc[p][q];
            f32x4 r;
            r[0] = __expf(-GAMMA * fmaxf(fmaf(-2.f, a[0], sa + sb.x), 0.f));
            r[1] = __expf(-GAMMA * fmaxf(fmaf(-2.f, a[1], sa + sb.y), 0.f));
            r[2] = __expf(-GAMMA * fmaxf(fmaf(-2.f, a[2], sa + sb.z), 0.f));
            r[3] = __expf(-GAMMA * fmaxf(fmaf(-2.f, a[3], sa + sb.w), 0.f));
            *(f32x4*)&wbuf[fr * 128 + (c ^ ((fr & 7) << 2))] = r;
        }
        // readback + NT store: 2 full rows x 512B contiguous per instruction
        const int half = lane >> 5, lc = lane & 31;
        #pragma unroll
        for (int i = 0; i < 8; ++i) {
            int rl = i * 2 + half;              // row_local 0..15
            f32x4 v = *(const f32x4*)&wbuf[rl * 128 + ((lc * 4) ^ ((rl & 7) << 2))];
            int grow = i0 + wr + p * 16 + rl;
            __builtin_nontemporal_store(v, (f32x4*)(out + (size_t)grow * N + j0 + lc * 4));
        }
    }
}

extern "C" void kernel_launch(void* const* d_in, const int* in_sizes, int n_in,
                              void* d_out, int out_size, void* d_ws, size_t ws_size,
                              hipStream_t stream) {
    (void)n_in; (void)ws_size; (void)out_size;
    const float* x = (const float*)d_in[0];
    float* out = (float*)d_out;
    const int K = 64;
    const int N = in_sizes[0] / K;   // 8192

    unsigned short* H = (unsigned short*)d_ws;       // N*64 fp16 = 1 MB
    float* sq = (float*)(H + (size_t)N * K);         // 32 KB

    quant_kernel<<<dim3(N * K / 4 / 256), dim3(256), 0, stream>>>(x, H, sq);
    rbf_mfma12<<<dim3(N / 128, N / 128), dim3(256), 0, stream>>>(H, sq, out, N);
}